// Round 5
// baseline (12249.746 us; speedup 1.0000x reference)
//
#include <hip/hip_runtime.h>
#include <hip/hip_bf16.h>

#define TT 100
#define BSQ 128
#define NB 2560
#define OBS 255
#define GATES 2048
#define KAUG 544
#define KSTR 552

typedef __attribute__((ext_vector_type(8))) short bf16x8;
typedef __attribute__((ext_vector_type(4))) float f32x4;

// output layout (floats)
#define OUT_S 0
#define OUT_EN 768000
#define OUT_LP 1024000
#define OUT_C 1280000

__device__ __forceinline__ float bf2f(unsigned short u){
  union { unsigned int i; float f; } v; v.i = ((unsigned int)u) << 16; return v.f;
}
__device__ __forceinline__ unsigned short f2bf(float f){
  union { float f; unsigned int i; } v; v.f = f;
  unsigned int r = v.i + 0x7fffu + ((v.i >> 16) & 1u);
  return (unsigned short)(r >> 16);
}
__device__ __forceinline__ float sigm(float x){ return 1.0f/(1.0f + __expf(-x)); }
__device__ __forceinline__ float tanh_f(float x){
  float e = __expf(-2.0f*fabsf(x));
  float r = (1.0f - e)/(1.0f + e);
  return copysignf(r, x);
}

// ---- prep: per-sequence time normalization ----
__global__ void k_tnorm(const float* __restrict__ times, float* __restrict__ tnorm){
  int b = threadIdx.x;
  float t0 = times[b*TT];
  float tT = times[b*TT + TT - 1];
  float inv = 1.0f/(tT - t0);
  for (int t = 0; t < TT; ++t) tnorm[b*TT + t] = (times[b*TT + t] - t0)*inv;
}

// ---- prep: bf16 weights, FRAGMENT-SWIZZLED for the scan.
// Logical Whh_aug[n=2048][k=544] = [W_hh | Wz(=Wih[:,256:259]+Wih[:,259:262]) | 0].
// Stored as Whh_swz[n_tile=128][kk=17][lane=64][j=8]: lane = l4*16+l15 supplies
// n = n_tile*16+l15, k = kk*32+l4*8+j  -> wave loads are contiguous 1KB.
// Wihe[2048][256] = W_ih[:, :256] (row-major, used by k_E only).
__global__ void k_wprep(const float* __restrict__ W_hh, const float* __restrict__ W_ih,
                        unsigned short* __restrict__ Whh_swz, unsigned short* __restrict__ Wihe){
  int n = blockIdx.x;
  int n_tile = n >> 4, l15 = n & 15;
  for (int k = threadIdx.x; k < KAUG; k += 64){
    float v;
    if (k < 512)       v = W_hh[(size_t)n*512 + k];
    else if (k < 515)  v = W_ih[(size_t)n*262 + 256 + (k-512)] + W_ih[(size_t)n*262 + 259 + (k-512)];
    else               v = 0.0f;
    int kk = k >> 5, rem = k & 31, l4 = rem >> 3, j = rem & 7;
    Whh_swz[((((size_t)n_tile*17 + kk)*64) + l4*16 + l15)*8 + j] = f2bf(v);
    if (k < 256) Wihe[(size_t)n*256 + k] = f2bf(W_ih[(size_t)n*262 + k]);
  }
}

// ---- prep: mean/std head as MFMA B operand, [16][544]; cols 0-2 = W_m, 3-5 = W_s, rest 0 ----
__global__ void k_wms(const float* __restrict__ W_m, const float* __restrict__ W_s,
                      unsigned short* __restrict__ Wms){
  for (int i = threadIdx.x + blockIdx.x*256; i < 16*KAUG; i += 256*gridDim.x){
    int nn = i / KAUG, k = i % KAUG;
    float v = 0.0f;
    if (k < 512){
      if (nn < 3)      v = W_m[(size_t)k*3 + nn];
      else if (nn < 6) v = W_s[(size_t)k*3 + (nn-3)];
    }
    Wms[i] = f2bf(v);
  }
}

// ---- prep: emb_bf[12800][256] = [y|tnorm] @ W_emb + b_emb (fp32 math, bf16 out) ----
__global__ __launch_bounds__(256) void k_emb(
    const float* __restrict__ y, const float* __restrict__ tnorm,
    const float* __restrict__ W_emb, const float* __restrict__ b_emb,
    unsigned short* __restrict__ emb_bf){
  __shared__ float yt[10][256];
  const int tid = threadIdx.x;
  const int r0 = blockIdx.x * 10;   // 10 rows per block, 1280 blocks (rows = bb*100+t)
  for (int i = tid; i < 10*256; i += 256){
    int r = i >> 8, k = i & 255;
    int row = r0 + r;
    yt[r][k] = (k < OBS) ? y[(size_t)row*OBS + k] : tnorm[row];
  }
  __syncthreads();
  const int j = tid;
  float acc[10];
  float bj = b_emb[j];
  #pragma unroll
  for (int r = 0; r < 10; ++r) acc[r] = bj;
  for (int k = 0; k < 256; ++k){
    float w = W_emb[(size_t)k*256 + j];
    #pragma unroll
    for (int r = 0; r < 10; ++r) acc[r] += yt[r][k]*w;
  }
  #pragma unroll
  for (int r = 0; r < 10; ++r) emb_bf[(size_t)(r0+r)*256 + j] = f2bf(acc[r]);
}

// ---- prep: E[12800][2048] = emb @ Wihe^T + (b_ih + b_hh), bf16 out, MFMA ----
__global__ __launch_bounds__(256) void k_E(
    const unsigned short* __restrict__ emb_bf,
    const unsigned short* __restrict__ Wihe,
    const float* __restrict__ b_ih, const float* __restrict__ b_hh,
    unsigned short* __restrict__ Ebf){
  const int tid = threadIdx.x, wid = tid >> 6, lane = tid & 63;
  const int l15 = lane & 15, l4 = lane >> 4;
  const int m0 = blockIdx.x * 64;
  const int n  = blockIdx.y * 64 + wid*16 + l15;
  f32x4 acc[4];
  #pragma unroll
  for (int i = 0; i < 4; ++i) acc[i] = (f32x4){0.f,0.f,0.f,0.f};
  for (int kk = 0; kk < 8; ++kk){
    bf16x8 b = *(const bf16x8*)(Wihe + (size_t)n*256 + kk*32 + l4*8);
    #pragma unroll
    for (int mt = 0; mt < 4; ++mt){
      bf16x8 a = *(const bf16x8*)(emb_bf + (size_t)(m0 + mt*16 + l15)*256 + kk*32 + l4*8);
      acc[mt] = __builtin_amdgcn_mfma_f32_16x16x32_bf16(a, b, acc[mt], 0, 0, 0);
    }
  }
  const float bias = b_ih[n] + b_hh[n];
  #pragma unroll
  for (int mt = 0; mt < 4; ++mt)
    #pragma unroll
    for (int r = 0; r < 4; ++r){
      int m = m0 + mt*16 + l4*4 + r;
      Ebf[(size_t)m*GATES + n] = f2bf(acc[mt][r] + bias);
    }
}

// ---- the scan: persistent, 80 WGs x 512 thr, 32 rows/WG, single h(+z) buffer in LDS ----
// Per step: [K-loop, kk outer, B-frag loaded once and reused by both row-tiles]
// -> elementwise (no LDS) -> B1 -> [write h_new] -> B2 -> [wave0: ms head, z] -> B3.
__global__ __launch_bounds__(512, 2) void k_scan(
    const unsigned short* __restrict__ Whh,   // swizzled [128][17][64][8] bf16
    const unsigned short* __restrict__ Ebf,   // [12800][2048] bf16
    const unsigned short* __restrict__ Wms,   // [16][544] bf16
    const float* __restrict__ eps,            // [100][2560][3]
    const float* __restrict__ b_m,
    const float* __restrict__ b_s,
    float* __restrict__ out){
  __shared__ __align__(16) unsigned short h_aug[32][KSTR];   // h | z | 0-pad
  __shared__ float ms_lds[32][8];

  const int tid  = threadIdx.x;
  const int wid  = tid >> 6;
  const int lane = tid & 63;
  const int l15  = lane & 15;
  const int l4   = lane >> 4;
  const int row0 = blockIdx.x * 32;

  for (int i = tid; i < 32*KSTR; i += 512) ((unsigned short*)h_aug)[i] = 0;

  float c_reg[2][4][4];
  #pragma unroll
  for (int a = 0; a < 2; ++a)
    #pragma unroll
    for (int b = 0; b < 4; ++b)
      #pragma unroll
      for (int c = 0; c < 4; ++c) c_reg[a][b][c] = 0.0f;

  // byte offsets into swizzled Whh for this wave's 16 (quadrant, col-tile) B fragments
  // frag i=(q,ci): n_tile = q*32 + wid*4 + ci; chunk base = n_tile*17*1024 + lane*16 bytes
  int woff[16];
  #pragma unroll
  for (int q = 0; q < 4; ++q)
    #pragma unroll
    for (int ci = 0; ci < 4; ++ci){
      int n_tile = q*32 + wid*4 + ci;
      woff[q*4+ci] = n_tile*17*1024 + lane*16;
    }

  const float bm0 = b_m[0], bm1 = b_m[1], bm2 = b_m[2];
  const float bs0 = b_s[0], bs1 = b_s[1], bs2 = b_s[2];
  const float C_LOG2PI = 1.83787706640934534f;

  __syncthreads();

  #pragma unroll 1
  for (int t = 0; t < TT; ++t){
    f32x4 acc[2][16];
    #pragma unroll
    for (int mt = 0; mt < 2; ++mt)
      #pragma unroll
      for (int i = 0; i < 16; ++i) acc[mt][i] = (f32x4){0.f,0.f,0.f,0.f};

    const unsigned short* arow0 = &h_aug[l15][l4*8];
    const unsigned short* arow1 = &h_aug[16 + l15][l4*8];
    for (int kk = 0; kk < 17; ++kk){
      bf16x8 a0 = *(const bf16x8*)(arow0 + kk*32);
      bf16x8 a1 = *(const bf16x8*)(arow1 + kk*32);
      #pragma unroll
      for (int i = 0; i < 16; ++i){
        bf16x8 bfr = *(const bf16x8*)((const unsigned char*)Whh + (woff[i] + kk*1024));
        acc[0][i] = __builtin_amdgcn_mfma_f32_16x16x32_bf16(a0, bfr, acc[0][i], 0, 0, 0);
        acc[1][i] = __builtin_amdgcn_mfma_f32_16x16x32_bf16(a1, bfr, acc[1][i], 0, 0, 0);
      }
    }

    // elementwise: gates -> c,h (registers + global only; no LDS touched)
    unsigned short hreg[2][4][4];
    #pragma unroll
    for (int mt = 0; mt < 2; ++mt)
      #pragma unroll
      for (int ci = 0; ci < 4; ++ci){
        const int hh = wid*64 + ci*16 + l15;
        #pragma unroll
        for (int r = 0; r < 4; ++r){
          const int m = mt*16 + l4*4 + r;
          const int b = row0 + m;
          const unsigned short* Erow = Ebf + (size_t)((b & 127)*TT + t) * GATES;
          float gi = acc[mt][0*4+ci][r] + bf2f(Erow[hh]);
          float gf = acc[mt][1*4+ci][r] + bf2f(Erow[512 + hh]);
          float gg = acc[mt][2*4+ci][r] + bf2f(Erow[1024 + hh]);
          float go = acc[mt][3*4+ci][r] + bf2f(Erow[1536 + hh]);
          float iv = sigm(gi), fv = sigm(gf), gv = tanh_f(gg), ov = sigm(go);
          float cn = fv * c_reg[mt][ci][r] + iv * gv;
          c_reg[mt][ci][r] = cn;
          float hn = ov * tanh_f(cn);
          hreg[mt][ci][r] = f2bf(hn);
          out[(size_t)OUT_C + (size_t)b*51200 + (size_t)hh*100 + t] = cn;
        }
      }
    __syncthreads();  // B1: all waves done reading h

    #pragma unroll
    for (int mt = 0; mt < 2; ++mt)
      #pragma unroll
      for (int ci = 0; ci < 4; ++ci){
        const int hh = wid*64 + ci*16 + l15;
        #pragma unroll
        for (int r = 0; r < 4; ++r)
          h_aug[mt*16 + l4*4 + r][hh] = hreg[mt][ci][r];
      }
    __syncthreads();  // B2: h_new fully in LDS

    if (wid == 0){
      // mean/std pre-activations via one 16-col MFMA head (k<512: h only)
      f32x4 a2[2];
      a2[0] = (f32x4){0.f,0.f,0.f,0.f}; a2[1] = (f32x4){0.f,0.f,0.f,0.f};
      for (int kk = 0; kk < 16; ++kk){
        bf16x8 bfr = *(const bf16x8*)(Wms + l15*KAUG + kk*32 + l4*8);
        #pragma unroll
        for (int mt = 0; mt < 2; ++mt){
          bf16x8 a = *(const bf16x8*)(&h_aug[mt*16 + l15][kk*32 + l4*8]);
          a2[mt] = __builtin_amdgcn_mfma_f32_16x16x32_bf16(a, bfr, a2[mt], 0, 0, 0);
        }
      }
      if (l15 < 6){
        #pragma unroll
        for (int mt = 0; mt < 2; ++mt)
          #pragma unroll
          for (int r = 0; r < 4; ++r)
            ms_lds[mt*16 + l4*4 + r][l15] = a2[mt][r];
      }
      __asm__ volatile("s_waitcnt lgkmcnt(0)" ::: "memory");  // in-wave DS ordering
      if (lane < 32){
        const int m = lane, b = row0 + m;
        float lp = 0.0f, en = 0.0f;
        #pragma unroll
        for (int d = 0; d < 3; ++d){
          float mu = ms_lds[m][d]     + ((d==0)?bm0:(d==1)?bm1:bm2);
          float sv = ms_lds[m][3 + d] + ((d==0)?bs0:(d==1)?bs1:bs2);
          float sp = (sv > 15.0f) ? sv : __logf(1.0f + __expf(sv));
          sp += 1e-4f;
          float ls = __logf(sp);
          float ev = eps[((size_t)t*NB + b)*3 + d];
          float z  = mu + sp*ev;
          h_aug[m][512 + d] = f2bf(z);             // z feedback (tiled via Wz fold)
          out[(size_t)OUT_S + (size_t)b*300 + t*3 + d] = z;
          lp += -0.5f*ev*ev - ls;
          en += ls;
        }
        out[(size_t)OUT_EN + (size_t)b*100 + t] = en + 1.5f + 1.5f*C_LOG2PI;
        out[(size_t)OUT_LP + (size_t)b*100 + t] = lp - 1.5f*C_LOG2PI;
      }
    }
    __syncthreads();  // B3: z ready
  }
}

extern "C" void kernel_launch(void* const* d_in, const int* in_sizes, int n_in,
                              void* d_out, int out_size, void* d_ws, size_t ws_size,
                              hipStream_t stream){
  const float* y     = (const float*)d_in[0];
  const float* times = (const float*)d_in[1];
  const float* eps   = (const float*)d_in[2];
  const float* W_emb = (const float*)d_in[3];
  const float* b_emb = (const float*)d_in[4];
  const float* W_ih  = (const float*)d_in[5];
  const float* W_hh  = (const float*)d_in[6];
  const float* b_ih  = (const float*)d_in[7];
  const float* b_hh  = (const float*)d_in[8];
  const float* W_m   = (const float*)d_in[9];
  const float* b_m   = (const float*)d_in[10];
  const float* W_s   = (const float*)d_in[11];
  const float* b_s_  = (const float*)d_in[12];
  float* out = (float*)d_out;

  unsigned char* ws = (unsigned char*)d_ws;
  // ws layout (all 16B aligned): tnorm f32[12800] | Whh_swz bf16[128*17*64*8] | Wihe bf16[2048*256]
  //                              | Wms bf16[16*544] | emb bf16[12800*256] | E bf16[12800*2048]
  float*          tnorm = (float*)(ws + 0);
  unsigned short* Whh   = (unsigned short*)(ws + 51200);
  unsigned short* Wihe  = (unsigned short*)(ws + 2279424);
  unsigned short* Wms   = (unsigned short*)(ws + 3328000);
  unsigned short* emb   = (unsigned short*)(ws + 3345408);
  unsigned short* Ebf   = (unsigned short*)(ws + 9899008);
  if (ws_size < 62327808u) return;  // deterministic guard: fail loudly, don't corrupt

  k_tnorm<<<1, 128, 0, stream>>>(times, tnorm);
  k_wprep<<<2048, 64, 0, stream>>>(W_hh, W_ih, Whh, Wihe);
  k_wms<<<34, 256, 0, stream>>>(W_m, W_s, Wms);
  k_emb<<<1280, 256, 0, stream>>>(y, tnorm, W_emb, b_emb, emb);
  k_E<<<dim3(200, 32), 256, 0, stream>>>(emb, Wihe, b_ih, b_hh, Ebf);

  k_scan<<<80, 512, 0, stream>>>(Whh, Ebf, Wms, eps, b_m, b_s_, out);
}